// Round 18
// baseline (248.475 us; speedup 1.0000x reference)
//
#include <hip/hip_runtime.h>

#define B_      64
#define C_      512
#define NNODE   128
#define NEDGE   1024
#define NLAYERS 8
#define EPS_    1e-5f

typedef __attribute__((ext_vector_type(8))) short bf16x8;
typedef __attribute__((ext_vector_type(4))) float f32x4;
typedef const __attribute__((address_space(1))) unsigned int* gas_p;
typedef __attribute__((address_space(3))) unsigned int* las_p;

__device__ __forceinline__ ushort f2b(float x) {
    unsigned u = __builtin_bit_cast(unsigned, x);
    unsigned r = (u + 0x7fffu + ((u >> 16) & 1u)) >> 16;
    return (ushort)r;
}
__device__ __forceinline__ float b2f(ushort h) {
    unsigned u = ((unsigned)h) << 16;
    return __builtin_bit_cast(float, u);
}

// Fragment layout for a [rows][512] bf16 matrix consumed as MFMA A/B operand:
//   frag[rowblk][mf][ks][lane][8]   lane=(lq<<4)|lr
//   element (row = base + mf*16 + lr, k = ks*32 + lq*8 + j)

// ---------------- graph prep: ONE single-block kernel ----------------
__global__ __launch_bounds__(256) void prep_k(const int* __restrict__ ei,
                                              ushort* __restrict__ Ah,
                                              ushort* __restrict__ Al) {
    __shared__ float A_L[NNODE * NNODE];   // 64 KB
    __shared__ int degI[NNODE];
    __shared__ float dinvL[NNODE];
    const int t = threadIdx.x;

    if (t < NNODE) degI[t] = 0;
    for (int i = t; i < NNODE * NNODE / 4; i += 256)
        *(f32x4*)&A_L[i * 4] = (f32x4){0.f, 0.f, 0.f, 0.f};
    __syncthreads();
    for (int e = t; e < NEDGE; e += 256) atomicAdd(&degI[ei[NEDGE + e]], 1);
    __syncthreads();
    if (t < NNODE) dinvL[t] = rsqrtf((float)degI[t] + 1.0f);
    __syncthreads();
    for (int e = t; e < NEDGE; e += 256) {
        int s = ei[e], d = ei[NEDGE + e];
        atomicAdd(&A_L[d * NNODE + s], dinvL[s] * dinvL[d]);
    }
    if (t < NNODE) atomicAdd(&A_L[t * NNODE + t], dinvL[t] * dinvL[t]);
    __syncthreads();
    for (int i = 0; i < 8; ++i) {
        int gid = i * 256 + t;               // 0..2047
        int lane = gid & 63, lr = lane & 15, lq = lane >> 4;
        int kk = (gid >> 6) & 3, mf = (gid >> 8) & 3, wm = (gid >> 10) & 1;
        int row = wm * 64 + mf * 16 + lr;
        int k = kk * 32 + lq * 8;
        ushort hh[8], ll[8];
#pragma unroll
        for (int j = 0; j < 8; ++j) {
            float v = A_L[row * NNODE + k + j];
            hh[j] = f2b(v);
            ll[j] = f2b(v - b2f(hh[j]));
        }
        *(int4*)&Ah[(size_t)gid * 8] = *(int4*)hh;
        *(int4*)&Al[(size_t)gid * 8] = *(int4*)ll;
    }
}

// ---------------- merged front-end: pool (blocks 0..2047) + wprep (2048..2559)
__global__ __launch_bounds__(256) void front_k(const float* __restrict__ rgb,
                                               const float* __restrict__ ir,
                                               const float* __restrict__ pos,
                                               const float* __restrict__ W,
                                               ushort* __restrict__ xh,
                                               ushort* __restrict__ xl,
                                               ushort* __restrict__ Wfh,
                                               ushort* __restrict__ Wfl) {
    __shared__ __align__(16) char lbuf[17408];
    const int t = threadIdx.x;
    const int bid = blockIdx.x;

    if (bid < 2048) {
        // ---------------- pool path ----------------
        float (*lds)[130] = (float(*)[130])lbuf;
        const int l = t & 63, wv = t >> 6;
        const int c0 = (bid & 31) * 16, b = bid >> 5;
        const int va = l >> 3, ha = l & 7;

        for (int i = 0; i < 8; i += 2) {
            f32x4 r[2][4];
#pragma unroll
            for (int j = 0; j < 2; ++j) {
                int p = wv * 8 + i + j;               // 0..31
                int src = p >> 4, cc = p & 15;
                const float* base = (src ? ir : rgb)
                    + ((size_t)(b * C_ + c0 + cc)) * 1024 + va * 128 + ha * 4;
#pragma unroll
                for (int r2 = 0; r2 < 4; ++r2)
                    r[j][r2] = __builtin_nontemporal_load((const f32x4*)(base + r2 * 32));
            }
#pragma unroll
            for (int j = 0; j < 2; ++j) {
                int p = wv * 8 + i + j;
                int src = p >> 4, cc = p & 15;
                float s = 0.f;
#pragma unroll
                for (int r2 = 0; r2 < 4; ++r2)
                    s += r[j][r2].x + r[j][r2].y + r[j][r2].z + r[j][r2].w;
                lds[cc][src * 64 + l] = s * 0.0625f;
            }
        }
        __syncthreads();

        const int n = t >> 1, cb = (t & 1) * 8;
        float v[8];
        {
            float4 p0 = *(const float4*)&pos[(size_t)n * C_ + c0 + cb];
            float4 p1 = *(const float4*)&pos[(size_t)n * C_ + c0 + cb + 4];
            v[0] = lds[cb + 0][n] + p0.x; v[1] = lds[cb + 1][n] + p0.y;
            v[2] = lds[cb + 2][n] + p0.z; v[3] = lds[cb + 3][n] + p0.w;
            v[4] = lds[cb + 4][n] + p1.x; v[5] = lds[cb + 5][n] + p1.y;
            v[6] = lds[cb + 6][n] + p1.z; v[7] = lds[cb + 7][n] + p1.w;
        }
        ushort hs[8], ls[8];
#pragma unroll
        for (int j = 0; j < 8; ++j) {
            hs[j] = f2b(v[j]);
            ls[j] = f2b(v[j] - b2f(hs[j]));
        }
        const int wm = n >> 6, mf = (n >> 4) & 3, lr = n & 15;
        const int c = c0 + cb;
        const int ks = c >> 5, lq = (c >> 3) & 3;
        size_t o = (((size_t)(b * 2 + wm) * 4 + mf) * 16 + ks) * 512 + (lq * 16 + lr) * 8;
        *(int4*)&xh[o] = *(int4*)&hs[0];
        *(int4*)&xl[o] = *(int4*)&ls[0];
    } else {
        // ---------------- wprep path ----------------
        float (*tl)[68] = (float(*)[68])lbuf;
        const int wid = bid - 2048;                 // 0..511
        const int n0 = (wid & 7) * 64, k0 = ((wid >> 3) & 7) * 64, l = wid >> 6;
        const float* Wl = W + (size_t)l * C_ * C_;
        {
            int kk = t >> 2, nc = (t & 3) * 16;
            const float* src = Wl + (size_t)(k0 + kk) * C_ + n0 + nc;
#pragma unroll
            for (int g = 0; g < 4; ++g)
                *(float4*)&tl[kk][nc + g * 4] = *(const float4*)(src + g * 4);
        }
        __syncthreads();
        {
            int nn = t >> 2, kc = (t & 3) * 16;
            int n = n0 + nn;
            int nb = n >> 4, lr = n & 15;
            ushort h[16], lo[16];
#pragma unroll
            for (int j = 0; j < 16; ++j) {
                float v = tl[kc + j][nn];
                h[j] = f2b(v);
                lo[j] = f2b(v - b2f(h[j]));
            }
#pragma unroll
            for (int g = 0; g < 2; ++g) {
                int kb = k0 + kc + g * 8;
                int ks = kb >> 5, lq = (kb >> 3) & 3;
                size_t o = (((size_t)l * 32 + nb) * 16 + ks) * 512 + (lq * 16 + lr) * 8;
                *(int4*)&Wfh[o] = *(int4*)&h[g * 8];
                *(int4*)&Wfl[o] = *(int4*)&lo[g * 8];
            }
        }
    }
}

// ---------------- fused layer: x' = relu(A @ (x @ W) + bias) ----------------
// grid 256 (XCD decode), 512 thr = 8 waves (2m x 4n), block tile 128x128,
// wave tile 64x32 (24 MFMA / 12KB LDS reads = 0.5 KB/MFMA, was 0.83).
// Stage-1 via global_load_lds DMA dedup, 2x32KB double buffer.
__global__ __launch_bounds__(512, 2) void gemm_fused_k(
    const ushort* __restrict__ Xfh, const ushort* __restrict__ Xfl,
    const ushort* __restrict__ Wfh, const ushort* __restrict__ Wfl,
    const ushort* __restrict__ Afh, const ushort* __restrict__ Afl,
    const float* __restrict__ bias,
    ushort* __restrict__ Yfh, ushort* __restrict__ Yfl) {
    __shared__ __align__(16) char smem[65536];   // 2x32KB dbuf; then sP 64KB; sT
    ushort* sPh = (ushort*)smem;                 // [128 n][128 m] swizzled
    ushort* sPl = (ushort*)(smem + 32768);
    float*  sT  = (float*)smem;                  // [128][68] n-half (reuse)

    const int t = threadIdx.x, lane = t & 63;
    const int wv = t >> 6, wm = wv >> 2, wn = wv & 3;
    const int lr = lane & 15, lq = lane >> 4;
    const int bid = blockIdx.x;
    const int xcd = bid & 7, slot = bid >> 3;     // slot 0..31
    const int b = xcd * 8 + (slot >> 2);
    const int nt = slot & 3;
    const int bn = nt * 128;

    // per-wave staging sources: 4 chunks (X-h, X-l, W-h, W-l), chunk idx = wv
    const ushort* srcXh = Xfh + (size_t)b * 65536 + (size_t)wv * 8192 + lane * 8;
    const ushort* srcXl = Xfl + (size_t)b * 65536 + (size_t)wv * 8192 + lane * 8;
    const ushort* srcWh = Wfh + (size_t)(nt * 8 + wv) * 8192 + lane * 8;
    const ushort* srcWl = Wfl + (size_t)(nt * 8 + wv) * 8192 + lane * 8;

#define STAGE(KS, BUF)                                                        \
    {                                                                         \
        char* dstb = smem + (BUF) * 32768;                                    \
        __builtin_amdgcn_global_load_lds((gas_p)(srcXh + (KS) * 512),         \
            (las_p)(dstb + wv * 1024), 16, 0, 0);                             \
        __builtin_amdgcn_global_load_lds((gas_p)(srcXl + (KS) * 512),         \
            (las_p)(dstb + (8 + wv) * 1024), 16, 0, 0);                       \
        __builtin_amdgcn_global_load_lds((gas_p)(srcWh + (KS) * 512),         \
            (las_p)(dstb + (16 + wv) * 1024), 16, 0, 0);                      \
        __builtin_amdgcn_global_load_lds((gas_p)(srcWl + (KS) * 512),         \
            (las_p)(dstb + (24 + wv) * 1024), 16, 0, 0);                      \
    }

    f32x4 acc[4][2];
#pragma unroll
    for (int i = 0; i < 4; ++i)
#pragma unroll
        for (int j = 0; j < 2; ++j) acc[i][j] = (f32x4){0.f, 0.f, 0.f, 0.f};

    float bv[2];
#pragma unroll
    for (int nf = 0; nf < 2; ++nf) bv[nf] = bias[bn + wn * 32 + nf * 16 + lr];

    STAGE(0, 0)
    int cur = 0;
    for (int ks = 0; ks < 16; ++ks) {
        __syncthreads();              // buf[cur] DMA complete; buf[cur^1] reads done
        if (ks < 15) STAGE(ks + 1, cur ^ 1)
        const char* sb = smem + cur * 32768;
        bf16x8 fah[4], fal[4], fbh[2], fbl[2];
#pragma unroll
        for (int mf = 0; mf < 4; ++mf) {
            fah[mf] = *(const bf16x8*)(sb + (wm * 4 + mf) * 1024 + lane * 16);
            fal[mf] = *(const bf16x8*)(sb + (8 + wm * 4 + mf) * 1024 + lane * 16);
        }
#pragma unroll
        for (int nf = 0; nf < 2; ++nf) {
            fbh[nf] = *(const bf16x8*)(sb + (16 + wn * 2 + nf) * 1024 + lane * 16);
            fbl[nf] = *(const bf16x8*)(sb + (24 + wn * 2 + nf) * 1024 + lane * 16);
        }
#pragma unroll
        for (int mf = 0; mf < 4; ++mf)
#pragma unroll
            for (int nf = 0; nf < 2; ++nf) {
                acc[mf][nf] = __builtin_amdgcn_mfma_f32_16x16x32_bf16(
                    fah[mf], fbh[nf], acc[mf][nf], 0, 0, 0);
                acc[mf][nf] = __builtin_amdgcn_mfma_f32_16x16x32_bf16(
                    fal[mf], fbh[nf], acc[mf][nf], 0, 0, 0);
                acc[mf][nf] = __builtin_amdgcn_mfma_f32_16x16x32_bf16(
                    fah[mf], fbl[nf], acc[mf][nf], 0, 0, 0);
            }
        cur ^= 1;
    }
#undef STAGE
    __syncthreads();   // all buffer reads drained before smem reuse as sP

    // ---- XW tile -> sP[n 128][m 128] swizzled bf16-pair (stage-2 B operand)
#pragma unroll
    for (int mf = 0; mf < 4; ++mf) {
        int gm = wm * 8 + mf * 2 + (lq >> 1);
        int moff = (lq & 1) * 4;
#pragma unroll
        for (int nf = 0; nf < 2; ++nf) {
            int n = wn * 32 + nf * 16 + lr;          // 0..127
            int addr = n * 128 + ((gm ^ (n & 15)) << 3) + moff;
            ushort4 hu, lu;
            float y0 = acc[mf][nf][0], y1 = acc[mf][nf][1];
            float y2 = acc[mf][nf][2], y3 = acc[mf][nf][3];
            hu.x = f2b(y0); lu.x = f2b(y0 - b2f(hu.x));
            hu.y = f2b(y1); lu.y = f2b(y1 - b2f(hu.y));
            hu.z = f2b(y2); lu.z = f2b(y2 - b2f(hu.z));
            hu.w = f2b(y3); lu.w = f2b(y3 - b2f(hu.w));
            *(ushort4*)&sPh[addr] = hu;
            *(ushort4*)&sPl[addr] = lu;
        }
    }
    __syncthreads();

    // ---- stage 2: acc2 = A(128x128) @ XW(tile); A frag-direct (64KB, L2-hot)
    f32x4 acc2[4][2];
#pragma unroll
    for (int i = 0; i < 4; ++i)
#pragma unroll
        for (int j = 0; j < 2; ++j) acc2[i][j] = (f32x4){0.f, 0.f, 0.f, 0.f};

#pragma unroll
    for (int kk = 0; kk < 4; ++kk) {
        bf16x8 gah[4], gal[4], gbh[2], gbl[2];
#pragma unroll
        for (int mf = 0; mf < 4; ++mf) {
            size_t o = (size_t)((wm * 4 + mf) * 4 + kk) * 512 + lane * 8;
            gah[mf] = *(const bf16x8*)&Afh[o];
            gal[mf] = *(const bf16x8*)&Afl[o];
        }
#pragma unroll
        for (int nf = 0; nf < 2; ++nf) {
            int n = wn * 32 + nf * 16 + lr;
            int g = (((kk * 4 + lq) ^ (n & 15)) << 3);
            gbh[nf] = *(const bf16x8*)&sPh[n * 128 + g];
            gbl[nf] = *(const bf16x8*)&sPl[n * 128 + g];
        }
#pragma unroll
        for (int mf = 0; mf < 4; ++mf)
#pragma unroll
            for (int nf = 0; nf < 2; ++nf) {
                acc2[mf][nf] = __builtin_amdgcn_mfma_f32_16x16x32_bf16(
                    gah[mf], gbh[nf], acc2[mf][nf], 0, 0, 0);
                acc2[mf][nf] = __builtin_amdgcn_mfma_f32_16x16x32_bf16(
                    gal[mf], gbh[nf], acc2[mf][nf], 0, 0, 0);
                acc2[mf][nf] = __builtin_amdgcn_mfma_f32_16x16x32_bf16(
                    gah[mf], gbl[nf], acc2[mf][nf], 0, 0, 0);
            }
    }

    // ---- bias + relu + transpose + frag store, two n-halves of 64
#pragma unroll
    for (int h = 0; h < 2; ++h) {
        __syncthreads();
        if ((wn >> 1) == h) {
#pragma unroll
            for (int mf = 0; mf < 4; ++mf)
#pragma unroll
                for (int nf = 0; nf < 2; ++nf) {
                    int mb = wm * 64 + mf * 16 + lq * 4;
                    int nl = (wn & 1) * 32 + nf * 16 + lr;   // 0..63 in half
#pragma unroll
                    for (int r = 0; r < 4; ++r) {
                        float y = fmaxf(acc2[mf][nf][r] + bv[nf], 0.0f);
                        sT[(mb + r) * 68 + nl] = y;
                    }
                }
        }
        __syncthreads();
        {
            const int m = t >> 2, seg = t & 3;
            const float* rp = &sT[m * 68 + seg * 16];
            ushort hs[16], ls[16];
#pragma unroll
            for (int j = 0; j < 16; ++j) {
                float y = rp[j];
                hs[j] = f2b(y);
                ls[j] = f2b(y - b2f(hs[j]));
            }
            const int wm2 = m >> 6, mf2 = (m >> 4) & 3, lr2 = m & 15;
#pragma unroll
            for (int g = 0; g < 2; ++g) {
                int n_g = bn + h * 64 + seg * 16 + g * 8;
                int ks2 = n_g >> 5, lq2 = (n_g >> 3) & 3;
                size_t o = (((size_t)(b * 2 + wm2) * 4 + mf2) * 16 + ks2) * 512
                         + (lq2 * 16 + lr2) * 8;
                *(int4*)&Yfh[o] = *(int4*)&hs[g * 8];
                *(int4*)&Yfl[o] = *(int4*)&ls[g * 8];
            }
        }
    }
}

// ---------------- LayerNorm + transposed write-out (frag-layout input) ----------------
__global__ __launch_bounds__(256) void ln_out_k(const ushort* __restrict__ xh,
                                                const ushort* __restrict__ xl,
                                                const float* __restrict__ lw,
                                                const float* __restrict__ lb,
                                                float* __restrict__ out) {
    __shared__ float tile[32][68];
    __shared__ float muA[64], invA[64];
    const int t = threadIdx.x, lane = t & 63, mf = t >> 6;
    const int lr = lane & 15, lq = lane >> 4;
    const int b = blockIdx.x & 63, wm = blockIdx.x >> 6;
    const size_t base = ((size_t)(b * 2 + wm) * 4 + mf) * 8192 + lane * 8;

    float s1 = 0.f, s2 = 0.f;
    for (int ks = 0; ks < 16; ++ks) {
        int4 hh = *(const int4*)&xh[base + ks * 512];
        int4 llv = *(const int4*)&xl[base + ks * 512];
        ushort* hp = (ushort*)&hh;
        ushort* lp = (ushort*)&llv;
#pragma unroll
        for (int j = 0; j < 8; ++j) {
            float v = b2f(hp[j]) + b2f(lp[j]);
            s1 += v;
            s2 += v * v;
        }
    }
    s1 += __shfl_xor(s1, 16); s2 += __shfl_xor(s2, 16);
    s1 += __shfl_xor(s1, 32); s2 += __shfl_xor(s2, 32);
    if (lq == 0) {
        float mu = s1 * (1.0f / C_);
        muA[mf * 16 + lr] = mu;
        invA[mf * 16 + lr] = rsqrtf(s2 * (1.0f / C_) - mu * mu + EPS_);
    }
    __syncthreads();

    const int p = mf * 16 + lr;
    const float mu = muA[p], inv = invA[p];
    const size_t ob = (size_t)wm * (B_ * C_ * 64) + (size_t)b * (C_ * 64);

    for (int ks = 0; ks < 16; ++ks) {
        {
            int4 hh = *(const int4*)&xh[base + ks * 512];
            int4 llv = *(const int4*)&xl[base + ks * 512];
            ushort* hp = (ushort*)&hh;
            ushort* lp = (ushort*)&llv;
            int c = ks * 32 + lq * 8;
            float4 w0 = *(const float4*)&lw[c];
            float4 w1 = *(const float4*)&lw[c + 4];
            float4 b0 = *(const float4*)&lb[c];
            float4 b1 = *(const float4*)&lb[c + 4];
            float wv_[8] = {w0.x, w0.y, w0.z, w0.w, w1.x, w1.y, w1.z, w1.w};
            float bb_[8] = {b0.x, b0.y, b0.z, b0.w, b1.x, b1.y, b1.z, b1.w};
#pragma unroll
            for (int j = 0; j < 8; ++j) {
                float v = b2f(hp[j]) + b2f(lp[j]);
                tile[lq * 8 + j][p] = (v - mu) * inv * wv_[j] + bb_[j];
            }
        }
        __syncthreads();
        {
            int ch = t >> 3, p0 = (t & 7) * 8;
            float4 v0 = *(const float4*)&tile[ch][p0];
            float4 v1 = *(const float4*)&tile[ch][p0 + 4];
            *(float4*)&out[ob + (size_t)(ks * 32 + ch) * 64 + p0] = v0;
            *(float4*)&out[ob + (size_t)(ks * 32 + ch) * 64 + p0 + 4] = v1;
        }
        __syncthreads();
    }
}

// ---------------- launch ----------------

extern "C" void kernel_launch(void* const* d_in, const int* in_sizes, int n_in,
                              void* d_out, int out_size, void* d_ws, size_t ws_size,
                              hipStream_t stream) {
    const float* rgb = (const float*)d_in[0];
    const float* ir  = (const float*)d_in[1];
    const int*   ei  = (const int*)d_in[2];
    const float* pos = (const float*)d_in[3];
    const float* Wg  = (const float*)d_in[4];
    const float* bg  = (const float*)d_in[5];
    const float* lw  = (const float*)d_in[6];
    const float* lb  = (const float*)d_in[7];
    float* out = (float*)d_out;

    char* ws = (char*)d_ws;
    ushort* x0h  = (ushort*)(ws);
    ushort* x0l  = (ushort*)(ws + 8388608);
    ushort* x1h  = (ushort*)(ws + 16777216);
    ushort* x1l  = (ushort*)(ws + 25165824);
    ushort* Wfh  = (ushort*)(ws + 33554432);
    ushort* Wfl  = (ushort*)(ws + 37748736);
    ushort* Afh  = (ushort*)(ws + 42009088);
    ushort* Afl  = (ushort*)(ws + 42041856);

    prep_k<<<1, 256, 0, stream>>>(ei, Afh, Afl);

    front_k<<<2560, 256, 0, stream>>>(rgb, ir, pos, Wg, x0h, x0l, Wfh, Wfl);

    for (int l = 0; l < NLAYERS; ++l) {
        const ushort* inh = (l & 1) ? x1h : x0h;
        const ushort* inl = (l & 1) ? x1l : x0l;
        ushort* outh = (l & 1) ? x0h : x1h;
        ushort* outl = (l & 1) ? x0l : x1l;
        gemm_fused_k<<<256, 512, 0, stream>>>(
            inh, inl, Wfh + (size_t)l * C_ * C_, Wfl + (size_t)l * C_ * C_,
            Afh, Afl, bg + (size_t)l * C_, outh, outl);
    }

    ln_out_k<<<2 * B_, 256, 0, stream>>>(x0h, x0l, lw, lb, out);
}

// Round 19
// 215.050 us; speedup vs baseline: 1.1554x; 1.1554x over previous
//
#include <hip/hip_runtime.h>

#define B_      64
#define C_      512
#define NNODE   128
#define NEDGE   1024
#define NLAYERS 8
#define EPS_    1e-5f

typedef __attribute__((ext_vector_type(8))) short bf16x8;
typedef __attribute__((ext_vector_type(4))) float f32x4;
typedef const __attribute__((address_space(1))) unsigned int* gas_p;
typedef __attribute__((address_space(3))) unsigned int* las_p;

__device__ __forceinline__ ushort f2b(float x) {
    unsigned u = __builtin_bit_cast(unsigned, x);
    unsigned r = (u + 0x7fffu + ((u >> 16) & 1u)) >> 16;
    return (ushort)r;
}
__device__ __forceinline__ float b2f(ushort h) {
    unsigned u = ((unsigned)h) << 16;
    return __builtin_bit_cast(float, u);
}

// Fragment layout for a [rows][512] bf16 matrix consumed as MFMA A/B operand:
//   frag[rowblk][mf][ks][lane][8]   lane=(lq<<4)|lr
//   element (row = base + mf*16 + lr, k = ks*32 + lq*8 + j)

// ---------------- graph prep: ONE single-block kernel ----------------
__global__ __launch_bounds__(256) void prep_k(const int* __restrict__ ei,
                                              ushort* __restrict__ Ah,
                                              ushort* __restrict__ Al) {
    __shared__ float A_L[NNODE * NNODE];   // 64 KB
    __shared__ int degI[NNODE];
    __shared__ float dinvL[NNODE];
    const int t = threadIdx.x;

    if (t < NNODE) degI[t] = 0;
    for (int i = t; i < NNODE * NNODE / 4; i += 256)
        *(f32x4*)&A_L[i * 4] = (f32x4){0.f, 0.f, 0.f, 0.f};
    __syncthreads();
    for (int e = t; e < NEDGE; e += 256) atomicAdd(&degI[ei[NEDGE + e]], 1);
    __syncthreads();
    if (t < NNODE) dinvL[t] = rsqrtf((float)degI[t] + 1.0f);
    __syncthreads();
    for (int e = t; e < NEDGE; e += 256) {
        int s = ei[e], d = ei[NEDGE + e];
        atomicAdd(&A_L[d * NNODE + s], dinvL[s] * dinvL[d]);
    }
    if (t < NNODE) atomicAdd(&A_L[t * NNODE + t], dinvL[t] * dinvL[t]);
    __syncthreads();
    for (int i = 0; i < 8; ++i) {
        int gid = i * 256 + t;               // 0..2047
        int lane = gid & 63, lr = lane & 15, lq = lane >> 4;
        int kk = (gid >> 6) & 3, mf = (gid >> 8) & 3, wm = (gid >> 10) & 1;
        int row = wm * 64 + mf * 16 + lr;
        int k = kk * 32 + lq * 8;
        ushort hh[8], ll[8];
#pragma unroll
        for (int j = 0; j < 8; ++j) {
            float v = A_L[row * NNODE + k + j];
            hh[j] = f2b(v);
            ll[j] = f2b(v - b2f(hh[j]));
        }
        *(int4*)&Ah[(size_t)gid * 8] = *(int4*)hh;
        *(int4*)&Al[(size_t)gid * 8] = *(int4*)ll;
    }
}

// ---------------- merged front-end: pool (blocks 0..2047) + wprep (2048..2559)
__global__ __launch_bounds__(256) void front_k(const float* __restrict__ rgb,
                                               const float* __restrict__ ir,
                                               const float* __restrict__ pos,
                                               const float* __restrict__ W,
                                               ushort* __restrict__ xh,
                                               ushort* __restrict__ xl,
                                               ushort* __restrict__ Wfh,
                                               ushort* __restrict__ Wfl) {
    __shared__ __align__(16) char lbuf[17408];
    const int t = threadIdx.x;
    const int bid = blockIdx.x;

    if (bid < 2048) {
        // ---------------- pool path ----------------
        float (*lds)[130] = (float(*)[130])lbuf;
        const int l = t & 63, wv = t >> 6;
        const int c0 = (bid & 31) * 16, b = bid >> 5;
        const int va = l >> 3, ha = l & 7;

        for (int i = 0; i < 8; i += 2) {
            f32x4 r[2][4];
#pragma unroll
            for (int j = 0; j < 2; ++j) {
                int p = wv * 8 + i + j;               // 0..31
                int src = p >> 4, cc = p & 15;
                const float* base = (src ? ir : rgb)
                    + ((size_t)(b * C_ + c0 + cc)) * 1024 + va * 128 + ha * 4;
#pragma unroll
                for (int r2 = 0; r2 < 4; ++r2)
                    r[j][r2] = __builtin_nontemporal_load((const f32x4*)(base + r2 * 32));
            }
#pragma unroll
            for (int j = 0; j < 2; ++j) {
                int p = wv * 8 + i + j;
                int src = p >> 4, cc = p & 15;
                float s = 0.f;
#pragma unroll
                for (int r2 = 0; r2 < 4; ++r2)
                    s += r[j][r2].x + r[j][r2].y + r[j][r2].z + r[j][r2].w;
                lds[cc][src * 64 + l] = s * 0.0625f;
            }
        }
        __syncthreads();

        const int n = t >> 1, cb = (t & 1) * 8;
        float v[8];
        {
            float4 p0 = *(const float4*)&pos[(size_t)n * C_ + c0 + cb];
            float4 p1 = *(const float4*)&pos[(size_t)n * C_ + c0 + cb + 4];
            v[0] = lds[cb + 0][n] + p0.x; v[1] = lds[cb + 1][n] + p0.y;
            v[2] = lds[cb + 2][n] + p0.z; v[3] = lds[cb + 3][n] + p0.w;
            v[4] = lds[cb + 4][n] + p1.x; v[5] = lds[cb + 5][n] + p1.y;
            v[6] = lds[cb + 6][n] + p1.z; v[7] = lds[cb + 7][n] + p1.w;
        }
        ushort hs[8], ls[8];
#pragma unroll
        for (int j = 0; j < 8; ++j) {
            hs[j] = f2b(v[j]);
            ls[j] = f2b(v[j] - b2f(hs[j]));
        }
        const int wm = n >> 6, mf = (n >> 4) & 3, lr = n & 15;
        const int c = c0 + cb;
        const int ks = c >> 5, lq = (c >> 3) & 3;
        size_t o = (((size_t)(b * 2 + wm) * 4 + mf) * 16 + ks) * 512 + (lq * 16 + lr) * 8;
        *(int4*)&xh[o] = *(int4*)&hs[0];
        *(int4*)&xl[o] = *(int4*)&ls[0];
    } else {
        // ---------------- wprep path ----------------
        float (*tl)[68] = (float(*)[68])lbuf;
        const int wid = bid - 2048;                 // 0..511
        const int n0 = (wid & 7) * 64, k0 = ((wid >> 3) & 7) * 64, l = wid >> 6;
        const float* Wl = W + (size_t)l * C_ * C_;
        {
            int kk = t >> 2, nc = (t & 3) * 16;
            const float* src = Wl + (size_t)(k0 + kk) * C_ + n0 + nc;
#pragma unroll
            for (int g = 0; g < 4; ++g)
                *(float4*)&tl[kk][nc + g * 4] = *(const float4*)(src + g * 4);
        }
        __syncthreads();
        {
            int nn = t >> 2, kc = (t & 3) * 16;
            int n = n0 + nn;
            int nb = n >> 4, lr = n & 15;
            ushort h[16], lo[16];
#pragma unroll
            for (int j = 0; j < 16; ++j) {
                float v = tl[kc + j][nn];
                h[j] = f2b(v);
                lo[j] = f2b(v - b2f(h[j]));
            }
#pragma unroll
            for (int g = 0; g < 2; ++g) {
                int kb = k0 + kc + g * 8;
                int ks = kb >> 5, lq = (kb >> 3) & 3;
                size_t o = (((size_t)l * 32 + nb) * 16 + ks) * 512 + (lq * 16 + lr) * 8;
                *(int4*)&Wfh[o] = *(int4*)&h[g * 8];
                *(int4*)&Wfl[o] = *(int4*)&lo[g * 8];
            }
        }
    }
}

// ---------------- fused layer: x' = relu(A @ (x @ W) + bias) ----------------
// grid 512 (XCD decode), 256 thr = 4 waves (2m x 2n), block tile 128m x 64n,
// wave tile 64x32 (24 MFMA / 12KB LDS reads = 0.5 KB/MFMA vs R17's 0.83).
// DMA-dedup staging (24 chunks/ks, 6 per wave), 2x24KB dbuf, 2 blocks/CU.
__global__ __launch_bounds__(256, 2) void gemm_fused_k(
    const ushort* __restrict__ Xfh, const ushort* __restrict__ Xfl,
    const ushort* __restrict__ Wfh, const ushort* __restrict__ Wfl,
    const ushort* __restrict__ Afh, const ushort* __restrict__ Afl,
    const float* __restrict__ bias,
    ushort* __restrict__ Yfh, ushort* __restrict__ Yfl) {
    __shared__ __align__(16) char smem[49152];   // 2x24KB dbuf; sP 32KB; sT 34.8KB
    ushort* sPh = (ushort*)smem;                 // [64 n][128 m] swizzled
    ushort* sPl = (ushort*)(smem + 16384);
    float*  sT  = (float*)smem;                  // [128][68] (reuse)

    const int t = threadIdx.x, lane = t & 63;
    const int wv = t >> 6, wm = wv >> 1, wn = wv & 1;
    const int lr = lane & 15, lq = lane >> 4;
    const int bid = blockIdx.x;
    const int xcd = bid & 7, slot = bid >> 3;     // slot 0..63
    const int b = xcd * 8 + (slot >> 3);
    const int nt8 = slot & 7;
    const int bn = nt8 * 64;

    // staging sources; wave wv stages 6 chunks: X-h {wv*2,wv*2+1}, X-l same,
    // W-h {wv}, W-l {wv}.  chunk = 1KB (512 ushorts), ks stride 512.
    const ushort* srcX0h = Xfh + (size_t)b * 65536 + (size_t)(wv * 2) * 8192 + lane * 8;
    const ushort* srcX1h = srcX0h + 8192;
    const ushort* srcX0l = Xfl + (size_t)b * 65536 + (size_t)(wv * 2) * 8192 + lane * 8;
    const ushort* srcX1l = srcX0l + 8192;
    const ushort* srcWh  = Wfh + (size_t)(nt8 * 4 + wv) * 8192 + lane * 8;
    const ushort* srcWl  = Wfl + (size_t)(nt8 * 4 + wv) * 8192 + lane * 8;

#define STAGE(KS, BUF)                                                        \
    {                                                                         \
        char* dstb = smem + (BUF) * 24576;                                    \
        __builtin_amdgcn_global_load_lds((gas_p)(srcX0h + (KS) * 512),        \
            (las_p)(dstb + (wv * 2 + 0) * 1024), 16, 0, 0);                   \
        __builtin_amdgcn_global_load_lds((gas_p)(srcX1h + (KS) * 512),        \
            (las_p)(dstb + (wv * 2 + 1) * 1024), 16, 0, 0);                   \
        __builtin_amdgcn_global_load_lds((gas_p)(srcX0l + (KS) * 512),        \
            (las_p)(dstb + (8 + wv * 2 + 0) * 1024), 16, 0, 0);               \
        __builtin_amdgcn_global_load_lds((gas_p)(srcX1l + (KS) * 512),        \
            (las_p)(dstb + (8 + wv * 2 + 1) * 1024), 16, 0, 0);               \
        __builtin_amdgcn_global_load_lds((gas_p)(srcWh + (KS) * 512),         \
            (las_p)(dstb + (16 + wv) * 1024), 16, 0, 0);                      \
        __builtin_amdgcn_global_load_lds((gas_p)(srcWl + (KS) * 512),         \
            (las_p)(dstb + (20 + wv) * 1024), 16, 0, 0);                      \
    }

    f32x4 acc[4][2];
#pragma unroll
    for (int i = 0; i < 4; ++i)
#pragma unroll
        for (int j = 0; j < 2; ++j) acc[i][j] = (f32x4){0.f, 0.f, 0.f, 0.f};

    float bv[2];
#pragma unroll
    for (int nf = 0; nf < 2; ++nf) bv[nf] = bias[bn + wn * 32 + nf * 16 + lr];

    STAGE(0, 0)
    int cur = 0;
    for (int ks = 0; ks < 16; ++ks) {
        __syncthreads();              // buf[cur] DMA complete; buf[cur^1] reads done
        if (ks < 15) STAGE(ks + 1, cur ^ 1)
        const char* sb = smem + cur * 24576;
        bf16x8 fah[4], fal[4], fbh[2], fbl[2];
#pragma unroll
        for (int mf = 0; mf < 4; ++mf) {
            fah[mf] = *(const bf16x8*)(sb + (wm * 4 + mf) * 1024 + lane * 16);
            fal[mf] = *(const bf16x8*)(sb + (8 + wm * 4 + mf) * 1024 + lane * 16);
        }
#pragma unroll
        for (int nf = 0; nf < 2; ++nf) {
            fbh[nf] = *(const bf16x8*)(sb + (16 + wn * 2 + nf) * 1024 + lane * 16);
            fbl[nf] = *(const bf16x8*)(sb + (20 + wn * 2 + nf) * 1024 + lane * 16);
        }
#pragma unroll
        for (int mf = 0; mf < 4; ++mf)
#pragma unroll
            for (int nf = 0; nf < 2; ++nf) {
                acc[mf][nf] = __builtin_amdgcn_mfma_f32_16x16x32_bf16(
                    fah[mf], fbh[nf], acc[mf][nf], 0, 0, 0);
                acc[mf][nf] = __builtin_amdgcn_mfma_f32_16x16x32_bf16(
                    fal[mf], fbh[nf], acc[mf][nf], 0, 0, 0);
                acc[mf][nf] = __builtin_amdgcn_mfma_f32_16x16x32_bf16(
                    fah[mf], fbl[nf], acc[mf][nf], 0, 0, 0);
            }
        cur ^= 1;
    }
#undef STAGE
    __syncthreads();   // all buffer reads drained before smem reuse as sP

    // ---- XW tile -> sP[n 64][m 128] swizzled bf16-pair (stage-2 B operand)
#pragma unroll
    for (int mf = 0; mf < 4; ++mf) {
        int gm = wm * 8 + mf * 2 + (lq >> 1);
        int moff = (lq & 1) * 4;
#pragma unroll
        for (int nf = 0; nf < 2; ++nf) {
            int n = wn * 32 + nf * 16 + lr;          // 0..63
            int addr = n * 128 + ((gm ^ (n & 15)) << 3) + moff;
            ushort4 hu, lu;
            float y0 = acc[mf][nf][0], y1 = acc[mf][nf][1];
            float y2 = acc[mf][nf][2], y3 = acc[mf][nf][3];
            hu.x = f2b(y0); lu.x = f2b(y0 - b2f(hu.x));
            hu.y = f2b(y1); lu.y = f2b(y1 - b2f(hu.y));
            hu.z = f2b(y2); lu.z = f2b(y2 - b2f(hu.z));
            hu.w = f2b(y3); lu.w = f2b(y3 - b2f(hu.w));
            *(ushort4*)&sPh[addr] = hu;
            *(ushort4*)&sPl[addr] = lu;
        }
    }
    __syncthreads();

    // ---- stage 2: acc2 = A(128x128) @ XW(tile); A frag-direct (64KB, L2-hot)
    f32x4 acc2[4][2];
#pragma unroll
    for (int i = 0; i < 4; ++i)
#pragma unroll
        for (int j = 0; j < 2; ++j) acc2[i][j] = (f32x4){0.f, 0.f, 0.f, 0.f};

#pragma unroll
    for (int kk = 0; kk < 4; ++kk) {
        bf16x8 gah[4], gal[4], gbh[2], gbl[2];
#pragma unroll
        for (int mf = 0; mf < 4; ++mf) {
            size_t o = (size_t)((wm * 4 + mf) * 4 + kk) * 512 + lane * 8;
            gah[mf] = *(const bf16x8*)&Afh[o];
            gal[mf] = *(const bf16x8*)&Afl[o];
        }
#pragma unroll
        for (int nf = 0; nf < 2; ++nf) {
            int n = wn * 32 + nf * 16 + lr;
            int g = (((kk * 4 + lq) ^ (n & 15)) << 3);
            gbh[nf] = *(const bf16x8*)&sPh[n * 128 + g];
            gbl[nf] = *(const bf16x8*)&sPl[n * 128 + g];
        }
#pragma unroll
        for (int mf = 0; mf < 4; ++mf)
#pragma unroll
            for (int nf = 0; nf < 2; ++nf) {
                acc2[mf][nf] = __builtin_amdgcn_mfma_f32_16x16x32_bf16(
                    gah[mf], gbh[nf], acc2[mf][nf], 0, 0, 0);
                acc2[mf][nf] = __builtin_amdgcn_mfma_f32_16x16x32_bf16(
                    gal[mf], gbh[nf], acc2[mf][nf], 0, 0, 0);
                acc2[mf][nf] = __builtin_amdgcn_mfma_f32_16x16x32_bf16(
                    gah[mf], gbl[nf], acc2[mf][nf], 0, 0, 0);
            }
    }
    __syncthreads();   // sP reads done before smem reuse as sT

    // ---- bias + relu -> sT[128 m][64 n], 4 waves disjoint, single pass
#pragma unroll
    for (int mf = 0; mf < 4; ++mf) {
#pragma unroll
        for (int nf = 0; nf < 2; ++nf) {
            int mb = wm * 64 + mf * 16 + lq * 4;
            int nl = wn * 32 + nf * 16 + lr;         // 0..63
#pragma unroll
            for (int r = 0; r < 4; ++r) {
                float y = fmaxf(acc2[mf][nf][r] + bv[nf], 0.0f);
                sT[(mb + r) * 68 + nl] = y;
            }
        }
    }
    __syncthreads();

    // ---- split + frag-layout store: m = t>>1, 32-n half = t&1
    {
        const int m = t >> 1, hw = t & 1;
        const float* rp = &sT[m * 68 + hw * 32];
        ushort hs[32], ls[32];
#pragma unroll
        for (int j = 0; j < 32; ++j) {
            float y = rp[j];
            hs[j] = f2b(y);
            ls[j] = f2b(y - b2f(hs[j]));
        }
        const int wm2 = m >> 6, mf2 = (m >> 4) & 3, lr2 = m & 15;
#pragma unroll
        for (int g = 0; g < 4; ++g) {
            int n_g = bn + hw * 32 + g * 8;
            int ks2 = n_g >> 5, lq2 = (n_g >> 3) & 3;
            size_t o = (((size_t)(b * 2 + wm2) * 4 + mf2) * 16 + ks2) * 512
                     + (lq2 * 16 + lr2) * 8;
            *(int4*)&Yfh[o] = *(int4*)&hs[g * 8];
            *(int4*)&Yfl[o] = *(int4*)&ls[g * 8];
        }
    }
}

// ---------------- LayerNorm + transposed write-out (frag-layout input) ----------------
__global__ __launch_bounds__(256) void ln_out_k(const ushort* __restrict__ xh,
                                                const ushort* __restrict__ xl,
                                                const float* __restrict__ lw,
                                                const float* __restrict__ lb,
                                                float* __restrict__ out) {
    __shared__ float tile[32][68];
    __shared__ float muA[64], invA[64];
    const int t = threadIdx.x, lane = t & 63, mf = t >> 6;
    const int lr = lane & 15, lq = lane >> 4;
    const int b = blockIdx.x & 63, wm = blockIdx.x >> 6;
    const size_t base = ((size_t)(b * 2 + wm) * 4 + mf) * 8192 + lane * 8;

    float s1 = 0.f, s2 = 0.f;
    for (int ks = 0; ks < 16; ++ks) {
        int4 hh = *(const int4*)&xh[base + ks * 512];
        int4 llv = *(const int4*)&xl[base + ks * 512];
        ushort* hp = (ushort*)&hh;
        ushort* lp = (ushort*)&llv;
#pragma unroll
        for (int j = 0; j < 8; ++j) {
            float v = b2f(hp[j]) + b2f(lp[j]);
            s1 += v;
            s2 += v * v;
        }
    }
    s1 += __shfl_xor(s1, 16); s2 += __shfl_xor(s2, 16);
    s1 += __shfl_xor(s1, 32); s2 += __shfl_xor(s2, 32);
    if (lq == 0) {
        float mu = s1 * (1.0f / C_);
        muA[mf * 16 + lr] = mu;
        invA[mf * 16 + lr] = rsqrtf(s2 * (1.0f / C_) - mu * mu + EPS_);
    }
    __syncthreads();

    const int p = mf * 16 + lr;
    const float mu = muA[p], inv = invA[p];
    const size_t ob = (size_t)wm * (B_ * C_ * 64) + (size_t)b * (C_ * 64);

    for (int ks = 0; ks < 16; ++ks) {
        {
            int4 hh = *(const int4*)&xh[base + ks * 512];
            int4 llv = *(const int4*)&xl[base + ks * 512];
            ushort* hp = (ushort*)&hh;
            ushort* lp = (ushort*)&llv;
            int c = ks * 32 + lq * 8;
            float4 w0 = *(const float4*)&lw[c];
            float4 w1 = *(const float4*)&lw[c + 4];
            float4 b0 = *(const float4*)&lb[c];
            float4 b1 = *(const float4*)&lb[c + 4];
            float wv_[8] = {w0.x, w0.y, w0.z, w0.w, w1.x, w1.y, w1.z, w1.w};
            float bb_[8] = {b0.x, b0.y, b0.z, b0.w, b1.x, b1.y, b1.z, b1.w};
#pragma unroll
            for (int j = 0; j < 8; ++j) {
                float v = b2f(hp[j]) + b2f(lp[j]);
                tile[lq * 8 + j][p] = (v - mu) * inv * wv_[j] + bb_[j];
            }
        }
        __syncthreads();
        {
            int ch = t >> 3, p0 = (t & 7) * 8;
            float4 v0 = *(const float4*)&tile[ch][p0];
            float4 v1 = *(const float4*)&tile[ch][p0 + 4];
            *(float4*)&out[ob + (size_t)(ks * 32 + ch) * 64 + p0] = v0;
            *(float4*)&out[ob + (size_t)(ks * 32 + ch) * 64 + p0 + 4] = v1;
        }
        __syncthreads();
    }
}

// ---------------- launch ----------------

extern "C" void kernel_launch(void* const* d_in, const int* in_sizes, int n_in,
                              void* d_out, int out_size, void* d_ws, size_t ws_size,
                              hipStream_t stream) {
    const float* rgb = (const float*)d_in[0];
    const float* ir  = (const float*)d_in[1];
    const int*   ei  = (const int*)d_in[2];
    const float* pos = (const float*)d_in[3];
    const float* Wg  = (const float*)d_in[4];
    const float* bg  = (const float*)d_in[5];
    const float* lw  = (const float*)d_in[6];
    const float* lb  = (const float*)d_in[7];
    float* out = (float*)d_out;

    char* ws = (char*)d_ws;
    ushort* x0h  = (ushort*)(ws);
    ushort* x0l  = (ushort*)(ws + 8388608);
    ushort* x1h  = (ushort*)(ws + 16777216);
    ushort* x1l  = (ushort*)(ws + 25165824);
    ushort* Wfh  = (ushort*)(ws + 33554432);
    ushort* Wfl  = (ushort*)(ws + 37748736);
    ushort* Afh  = (ushort*)(ws + 42009088);
    ushort* Afl  = (ushort*)(ws + 42041856);

    prep_k<<<1, 256, 0, stream>>>(ei, Afh, Afl);

    front_k<<<2560, 256, 0, stream>>>(rgb, ir, pos, Wg, x0h, x0l, Wfh, Wfl);

    for (int l = 0; l < NLAYERS; ++l) {
        const ushort* inh = (l & 1) ? x1h : x0h;
        const ushort* inl = (l & 1) ? x1l : x0l;
        ushort* outh = (l & 1) ? x0h : x1h;
        ushort* outl = (l & 1) ? x0l : x1l;
        gemm_fused_k<<<512, 256, 0, stream>>>(
            inh, inl, Wfh + (size_t)l * C_ * C_, Wfl + (size_t)l * C_ * C_,
            Afh, Afl, bg + (size_t)l * C_, outh, outl);
    }

    ln_out_k<<<2 * B_, 256, 0, stream>>>(x0h, x0l, lw, lb, out);
}

// Round 20
// 213.004 us; speedup vs baseline: 1.1665x; 1.0096x over previous
//
#include <hip/hip_runtime.h>

#define B_      64
#define C_      512
#define NNODE   128
#define NEDGE   1024
#define NLAYERS 8
#define EPS_    1e-5f

typedef __attribute__((ext_vector_type(8))) short bf16x8;
typedef __attribute__((ext_vector_type(4))) float f32x4;
typedef const __attribute__((address_space(1))) unsigned int* gas_p;
typedef __attribute__((address_space(3))) unsigned int* las_p;

__device__ __forceinline__ ushort f2b(float x) {
    unsigned u = __builtin_bit_cast(unsigned, x);
    unsigned r = (u + 0x7fffu + ((u >> 16) & 1u)) >> 16;
    return (ushort)r;
}
__device__ __forceinline__ float b2f(ushort h) {
    unsigned u = ((unsigned)h) << 16;
    return __builtin_bit_cast(float, u);
}

// Fragment layout for a [rows][512] bf16 matrix consumed as MFMA A/B operand:
//   frag[rowblk][mf][ks][lane][8]   lane=(lq<<4)|lr
//   element (row = base + mf*16 + lr, k = ks*32 + lq*8 + j)

// ---------------- graph prep: ONE single-block kernel ----------------
__global__ __launch_bounds__(256) void prep_k(const int* __restrict__ ei,
                                              ushort* __restrict__ Ah,
                                              ushort* __restrict__ Al) {
    __shared__ float A_L[NNODE * NNODE];   // 64 KB
    __shared__ int degI[NNODE];
    __shared__ float dinvL[NNODE];
    const int t = threadIdx.x;

    if (t < NNODE) degI[t] = 0;
    for (int i = t; i < NNODE * NNODE / 4; i += 256)
        *(f32x4*)&A_L[i * 4] = (f32x4){0.f, 0.f, 0.f, 0.f};
    __syncthreads();
    for (int e = t; e < NEDGE; e += 256) atomicAdd(&degI[ei[NEDGE + e]], 1);
    __syncthreads();
    if (t < NNODE) dinvL[t] = rsqrtf((float)degI[t] + 1.0f);
    __syncthreads();
    for (int e = t; e < NEDGE; e += 256) {
        int s = ei[e], d = ei[NEDGE + e];
        atomicAdd(&A_L[d * NNODE + s], dinvL[s] * dinvL[d]);
    }
    if (t < NNODE) atomicAdd(&A_L[t * NNODE + t], dinvL[t] * dinvL[t]);
    __syncthreads();
    for (int i = 0; i < 8; ++i) {
        int gid = i * 256 + t;               // 0..2047
        int lane = gid & 63, lr = lane & 15, lq = lane >> 4;
        int kk = (gid >> 6) & 3, mf = (gid >> 8) & 3, wm = (gid >> 10) & 1;
        int row = wm * 64 + mf * 16 + lr;
        int k = kk * 32 + lq * 8;
        ushort hh[8], ll[8];
#pragma unroll
        for (int j = 0; j < 8; ++j) {
            float v = A_L[row * NNODE + k + j];
            hh[j] = f2b(v);
            ll[j] = f2b(v - b2f(hh[j]));
        }
        *(int4*)&Ah[(size_t)gid * 8] = *(int4*)hh;
        *(int4*)&Al[(size_t)gid * 8] = *(int4*)ll;
    }
}

// ---------------- merged front-end: pool (blocks 0..2047) + wprep (2048..2559)
// pool: 4 planes of nt-loads in flight (16 loads, 256B/lane) for latency cover.
__global__ __launch_bounds__(256) void front_k(const float* __restrict__ rgb,
                                               const float* __restrict__ ir,
                                               const float* __restrict__ pos,
                                               const float* __restrict__ W,
                                               ushort* __restrict__ xh,
                                               ushort* __restrict__ xl,
                                               ushort* __restrict__ Wfh,
                                               ushort* __restrict__ Wfl) {
    __shared__ __align__(16) char lbuf[17408];
    const int t = threadIdx.x;
    const int bid = blockIdx.x;

    if (bid < 2048) {
        // ---------------- pool path ----------------
        float (*lds)[130] = (float(*)[130])lbuf;
        const int l = t & 63, wv = t >> 6;
        const int c0 = (bid & 31) * 16, b = bid >> 5;
        const int va = l >> 3, ha = l & 7;

#pragma unroll
        for (int i = 0; i < 8; i += 4) {
            f32x4 r[4][4];
#pragma unroll
            for (int j = 0; j < 4; ++j) {
                int p = wv * 8 + i + j;               // 0..31
                int src = p >> 4, cc = p & 15;
                const float* base = (src ? ir : rgb)
                    + ((size_t)(b * C_ + c0 + cc)) * 1024 + va * 128 + ha * 4;
#pragma unroll
                for (int r2 = 0; r2 < 4; ++r2)
                    r[j][r2] = __builtin_nontemporal_load((const f32x4*)(base + r2 * 32));
            }
#pragma unroll
            for (int j = 0; j < 4; ++j) {
                int p = wv * 8 + i + j;
                int src = p >> 4, cc = p & 15;
                float s = 0.f;
#pragma unroll
                for (int r2 = 0; r2 < 4; ++r2)
                    s += r[j][r2].x + r[j][r2].y + r[j][r2].z + r[j][r2].w;
                lds[cc][src * 64 + l] = s * 0.0625f;
            }
        }
        __syncthreads();

        const int n = t >> 1, cb = (t & 1) * 8;
        float v[8];
        {
            float4 p0 = *(const float4*)&pos[(size_t)n * C_ + c0 + cb];
            float4 p1 = *(const float4*)&pos[(size_t)n * C_ + c0 + cb + 4];
            v[0] = lds[cb + 0][n] + p0.x; v[1] = lds[cb + 1][n] + p0.y;
            v[2] = lds[cb + 2][n] + p0.z; v[3] = lds[cb + 3][n] + p0.w;
            v[4] = lds[cb + 4][n] + p1.x; v[5] = lds[cb + 5][n] + p1.y;
            v[6] = lds[cb + 6][n] + p1.z; v[7] = lds[cb + 7][n] + p1.w;
        }
        ushort hs[8], ls[8];
#pragma unroll
        for (int j = 0; j < 8; ++j) {
            hs[j] = f2b(v[j]);
            ls[j] = f2b(v[j] - b2f(hs[j]));
        }
        const int wm = n >> 6, mf = (n >> 4) & 3, lr = n & 15;
        const int c = c0 + cb;
        const int ks = c >> 5, lq = (c >> 3) & 3;
        size_t o = (((size_t)(b * 2 + wm) * 4 + mf) * 16 + ks) * 512 + (lq * 16 + lr) * 8;
        *(int4*)&xh[o] = *(int4*)&hs[0];
        *(int4*)&xl[o] = *(int4*)&ls[0];
    } else {
        // ---------------- wprep path ----------------
        float (*tl)[68] = (float(*)[68])lbuf;
        const int wid = bid - 2048;                 // 0..511
        const int n0 = (wid & 7) * 64, k0 = ((wid >> 3) & 7) * 64, l = wid >> 6;
        const float* Wl = W + (size_t)l * C_ * C_;
        {
            int kk = t >> 2, nc = (t & 3) * 16;
            const float* src = Wl + (size_t)(k0 + kk) * C_ + n0 + nc;
#pragma unroll
            for (int g = 0; g < 4; ++g)
                *(float4*)&tl[kk][nc + g * 4] = *(const float4*)(src + g * 4);
        }
        __syncthreads();
        {
            int nn = t >> 2, kc = (t & 3) * 16;
            int n = n0 + nn;
            int nb = n >> 4, lr = n & 15;
            ushort h[16], lo[16];
#pragma unroll
            for (int j = 0; j < 16; ++j) {
                float v = tl[kc + j][nn];
                h[j] = f2b(v);
                lo[j] = f2b(v - b2f(h[j]));
            }
#pragma unroll
            for (int g = 0; g < 2; ++g) {
                int kb = k0 + kc + g * 8;
                int ks = kb >> 5, lq = (kb >> 3) & 3;
                size_t o = (((size_t)l * 32 + nb) * 16 + ks) * 512 + (lq * 16 + lr) * 8;
                *(int4*)&Wfh[o] = *(int4*)&h[g * 8];
                *(int4*)&Wfl[o] = *(int4*)&lo[g * 8];
            }
        }
    }
}

// ---------------- fused layer: x' = relu(A @ (x @ W) + bias) ----------------
// grid 512 (XCD decode), 256 thr = 4 waves (2m x 2n), block tile 128m x 64n,
// wave tile 64x32 (0.5 KB LDS reads per MFMA). DMA-dedup staging, 2x24KB dbuf,
// 2 blocks/CU.
__global__ __launch_bounds__(256, 2) void gemm_fused_k(
    const ushort* __restrict__ Xfh, const ushort* __restrict__ Xfl,
    const ushort* __restrict__ Wfh, const ushort* __restrict__ Wfl,
    const ushort* __restrict__ Afh, const ushort* __restrict__ Afl,
    const float* __restrict__ bias,
    ushort* __restrict__ Yfh, ushort* __restrict__ Yfl) {
    __shared__ __align__(16) char smem[49152];   // 2x24KB dbuf; sP 32KB; sT 34.8KB
    ushort* sPh = (ushort*)smem;                 // [64 n][128 m] swizzled
    ushort* sPl = (ushort*)(smem + 16384);
    float*  sT  = (float*)smem;                  // [128][68] (reuse)

    const int t = threadIdx.x, lane = t & 63;
    const int wv = t >> 6, wm = wv >> 1, wn = wv & 1;
    const int lr = lane & 15, lq = lane >> 4;
    const int bid = blockIdx.x;
    const int xcd = bid & 7, slot = bid >> 3;     // slot 0..63
    const int b = xcd * 8 + (slot >> 3);
    const int nt8 = slot & 7;
    const int bn = nt8 * 64;

    const ushort* srcX0h = Xfh + (size_t)b * 65536 + (size_t)(wv * 2) * 8192 + lane * 8;
    const ushort* srcX1h = srcX0h + 8192;
    const ushort* srcX0l = Xfl + (size_t)b * 65536 + (size_t)(wv * 2) * 8192 + lane * 8;
    const ushort* srcX1l = srcX0l + 8192;
    const ushort* srcWh  = Wfh + (size_t)(nt8 * 4 + wv) * 8192 + lane * 8;
    const ushort* srcWl  = Wfl + (size_t)(nt8 * 4 + wv) * 8192 + lane * 8;

#define STAGE(KS, BUF)                                                        \
    {                                                                         \
        char* dstb = smem + (BUF) * 24576;                                    \
        __builtin_amdgcn_global_load_lds((gas_p)(srcX0h + (KS) * 512),        \
            (las_p)(dstb + (wv * 2 + 0) * 1024), 16, 0, 0);                   \
        __builtin_amdgcn_global_load_lds((gas_p)(srcX1h + (KS) * 512),        \
            (las_p)(dstb + (wv * 2 + 1) * 1024), 16, 0, 0);                   \
        __builtin_amdgcn_global_load_lds((gas_p)(srcX0l + (KS) * 512),        \
            (las_p)(dstb + (8 + wv * 2 + 0) * 1024), 16, 0, 0);               \
        __builtin_amdgcn_global_load_lds((gas_p)(srcX1l + (KS) * 512),        \
            (las_p)(dstb + (8 + wv * 2 + 1) * 1024), 16, 0, 0);               \
        __builtin_amdgcn_global_load_lds((gas_p)(srcWh + (KS) * 512),         \
            (las_p)(dstb + (16 + wv) * 1024), 16, 0, 0);                      \
        __builtin_amdgcn_global_load_lds((gas_p)(srcWl + (KS) * 512),         \
            (las_p)(dstb + (20 + wv) * 1024), 16, 0, 0);                      \
    }

    f32x4 acc[4][2];
#pragma unroll
    for (int i = 0; i < 4; ++i)
#pragma unroll
        for (int j = 0; j < 2; ++j) acc[i][j] = (f32x4){0.f, 0.f, 0.f, 0.f};

    float bv[2];
#pragma unroll
    for (int nf = 0; nf < 2; ++nf) bv[nf] = bias[bn + wn * 32 + nf * 16 + lr];

    STAGE(0, 0)
    int cur = 0;
    for (int ks = 0; ks < 16; ++ks) {
        __syncthreads();              // buf[cur] DMA complete; buf[cur^1] reads done
        if (ks < 15) STAGE(ks + 1, cur ^ 1)
        const char* sb = smem + cur * 24576;
        bf16x8 fah[4], fal[4], fbh[2], fbl[2];
#pragma unroll
        for (int mf = 0; mf < 4; ++mf) {
            fah[mf] = *(const bf16x8*)(sb + (wm * 4 + mf) * 1024 + lane * 16);
            fal[mf] = *(const bf16x8*)(sb + (8 + wm * 4 + mf) * 1024 + lane * 16);
        }
#pragma unroll
        for (int nf = 0; nf < 2; ++nf) {
            fbh[nf] = *(const bf16x8*)(sb + (16 + wn * 2 + nf) * 1024 + lane * 16);
            fbl[nf] = *(const bf16x8*)(sb + (20 + wn * 2 + nf) * 1024 + lane * 16);
        }
#pragma unroll
        for (int mf = 0; mf < 4; ++mf)
#pragma unroll
            for (int nf = 0; nf < 2; ++nf) {
                acc[mf][nf] = __builtin_amdgcn_mfma_f32_16x16x32_bf16(
                    fah[mf], fbh[nf], acc[mf][nf], 0, 0, 0);
                acc[mf][nf] = __builtin_amdgcn_mfma_f32_16x16x32_bf16(
                    fal[mf], fbh[nf], acc[mf][nf], 0, 0, 0);
                acc[mf][nf] = __builtin_amdgcn_mfma_f32_16x16x32_bf16(
                    fah[mf], fbl[nf], acc[mf][nf], 0, 0, 0);
            }
        cur ^= 1;
    }
#undef STAGE
    __syncthreads();   // all buffer reads drained before smem reuse as sP

    // ---- XW tile -> sP[n 64][m 128] swizzled bf16-pair (stage-2 B operand)
#pragma unroll
    for (int mf = 0; mf < 4; ++mf) {
        int gm = wm * 8 + mf * 2 + (lq >> 1);
        int moff = (lq & 1) * 4;
#pragma unroll
        for (int nf = 0; nf < 2; ++nf) {
            int n = wn * 32 + nf * 16 + lr;          // 0..63
            int addr = n * 128 + ((gm ^ (n & 15)) << 3) + moff;
            ushort4 hu, lu;
            float y0 = acc[mf][nf][0], y1 = acc[mf][nf][1];
            float y2 = acc[mf][nf][2], y3 = acc[mf][nf][3];
            hu.x = f2b(y0); lu.x = f2b(y0 - b2f(hu.x));
            hu.y = f2b(y1); lu.y = f2b(y1 - b2f(hu.y));
            hu.z = f2b(y2); lu.z = f2b(y2 - b2f(hu.z));
            hu.w = f2b(y3); lu.w = f2b(y3 - b2f(hu.w));
            *(ushort4*)&sPh[addr] = hu;
            *(ushort4*)&sPl[addr] = lu;
        }
    }
    __syncthreads();

    // ---- stage 2: acc2 = A(128x128) @ XW(tile); A frag-direct (64KB, L2-hot)
    f32x4 acc2[4][2];
#pragma unroll
    for (int i = 0; i < 4; ++i)
#pragma unroll
        for (int j = 0; j < 2; ++j) acc2[i][j] = (f32x4){0.f, 0.f, 0.f, 0.f};

#pragma unroll
    for (int kk = 0; kk < 4; ++kk) {
        bf16x8 gah[4], gal[4], gbh[2], gbl[2];
#pragma unroll
        for (int mf = 0; mf < 4; ++mf) {
            size_t o = (size_t)((wm * 4 + mf) * 4 + kk) * 512 + lane * 8;
            gah[mf] = *(const bf16x8*)&Afh[o];
            gal[mf] = *(const bf16x8*)&Afl[o];
        }
#pragma unroll
        for (int nf = 0; nf < 2; ++nf) {
            int n = wn * 32 + nf * 16 + lr;
            int g = (((kk * 4 + lq) ^ (n & 15)) << 3);
            gbh[nf] = *(const bf16x8*)&sPh[n * 128 + g];
            gbl[nf] = *(const bf16x8*)&sPl[n * 128 + g];
        }
#pragma unroll
        for (int mf = 0; mf < 4; ++mf)
#pragma unroll
            for (int nf = 0; nf < 2; ++nf) {
                acc2[mf][nf] = __builtin_amdgcn_mfma_f32_16x16x32_bf16(
                    gah[mf], gbh[nf], acc2[mf][nf], 0, 0, 0);
                acc2[mf][nf] = __builtin_amdgcn_mfma_f32_16x16x32_bf16(
                    gal[mf], gbh[nf], acc2[mf][nf], 0, 0, 0);
                acc2[mf][nf] = __builtin_amdgcn_mfma_f32_16x16x32_bf16(
                    gah[mf], gbl[nf], acc2[mf][nf], 0, 0, 0);
            }
    }
    __syncthreads();   // sP reads done before smem reuse as sT

    // ---- bias + relu -> sT[128 m][64 n], 4 waves disjoint, single pass
#pragma unroll
    for (int mf = 0; mf < 4; ++mf) {
#pragma unroll
        for (int nf = 0; nf < 2; ++nf) {
            int mb = wm * 64 + mf * 16 + lq * 4;
            int nl = wn * 32 + nf * 16 + lr;         // 0..63
#pragma unroll
            for (int r = 0; r < 4; ++r) {
                float y = fmaxf(acc2[mf][nf][r] + bv[nf], 0.0f);
                sT[(mb + r) * 68 + nl] = y;
            }
        }
    }
    __syncthreads();

    // ---- split + frag-layout store: m = t>>1, 32-n half = t&1
    {
        const int m = t >> 1, hw = t & 1;
        const float* rp = &sT[m * 68 + hw * 32];
        ushort hs[32], ls[32];
#pragma unroll
        for (int j = 0; j < 32; ++j) {
            float y = rp[j];
            hs[j] = f2b(y);
            ls[j] = f2b(y - b2f(hs[j]));
        }
        const int wm2 = m >> 6, mf2 = (m >> 4) & 3, lr2 = m & 15;
#pragma unroll
        for (int g = 0; g < 4; ++g) {
            int n_g = bn + hw * 32 + g * 8;
            int ks2 = n_g >> 5, lq2 = (n_g >> 3) & 3;
            size_t o = (((size_t)(b * 2 + wm2) * 4 + mf2) * 16 + ks2) * 512
                     + (lq2 * 16 + lr2) * 8;
            *(int4*)&Yfh[o] = *(int4*)&hs[g * 8];
            *(int4*)&Yfl[o] = *(int4*)&ls[g * 8];
        }
    }
}

// ---------------- LayerNorm + transposed write-out (frag-layout input) ----------------
__global__ __launch_bounds__(256) void ln_out_k(const ushort* __restrict__ xh,
                                                const ushort* __restrict__ xl,
                                                const float* __restrict__ lw,
                                                const float* __restrict__ lb,
                                                float* __restrict__ out) {
    __shared__ float tile[32][68];
    __shared__ float muA[64], invA[64];
    const int t = threadIdx.x, lane = t & 63, mf = t >> 6;
    const int lr = lane & 15, lq = lane >> 4;
    const int b = blockIdx.x & 63, wm = blockIdx.x >> 6;
    const size_t base = ((size_t)(b * 2 + wm) * 4 + mf) * 8192 + lane * 8;

    float s1 = 0.f, s2 = 0.f;
    for (int ks = 0; ks < 16; ++ks) {
        int4 hh = *(const int4*)&xh[base + ks * 512];
        int4 llv = *(const int4*)&xl[base + ks * 512];
        ushort* hp = (ushort*)&hh;
        ushort* lp = (ushort*)&llv;
#pragma unroll
        for (int j = 0; j < 8; ++j) {
            float v = b2f(hp[j]) + b2f(lp[j]);
            s1 += v;
            s2 += v * v;
        }
    }
    s1 += __shfl_xor(s1, 16); s2 += __shfl_xor(s2, 16);
    s1 += __shfl_xor(s1, 32); s2 += __shfl_xor(s2, 32);
    if (lq == 0) {
        float mu = s1 * (1.0f / C_);
        muA[mf * 16 + lr] = mu;
        invA[mf * 16 + lr] = rsqrtf(s2 * (1.0f / C_) - mu * mu + EPS_);
    }
    __syncthreads();

    const int p = mf * 16 + lr;
    const float mu = muA[p], inv = invA[p];
    const size_t ob = (size_t)wm * (B_ * C_ * 64) + (size_t)b * (C_ * 64);

    for (int ks = 0; ks < 16; ++ks) {
        {
            int4 hh = *(const int4*)&xh[base + ks * 512];
            int4 llv = *(const int4*)&xl[base + ks * 512];
            ushort* hp = (ushort*)&hh;
            ushort* lp = (ushort*)&llv;
            int c = ks * 32 + lq * 8;
            float4 w0 = *(const float4*)&lw[c];
            float4 w1 = *(const float4*)&lw[c + 4];
            float4 b0 = *(const float4*)&lb[c];
            float4 b1 = *(const float4*)&lb[c + 4];
            float wv_[8] = {w0.x, w0.y, w0.z, w0.w, w1.x, w1.y, w1.z, w1.w};
            float bb_[8] = {b0.x, b0.y, b0.z, b0.w, b1.x, b1.y, b1.z, b1.w};
#pragma unroll
            for (int j = 0; j < 8; ++j) {
                float v = b2f(hp[j]) + b2f(lp[j]);
                tile[lq * 8 + j][p] = (v - mu) * inv * wv_[j] + bb_[j];
            }
        }
        __syncthreads();
        {
            int ch = t >> 3, p0 = (t & 7) * 8;
            float4 v0 = *(const float4*)&tile[ch][p0];
            float4 v1 = *(const float4*)&tile[ch][p0 + 4];
            *(float4*)&out[ob + (size_t)(ks * 32 + ch) * 64 + p0] = v0;
            *(float4*)&out[ob + (size_t)(ks * 32 + ch) * 64 + p0 + 4] = v1;
        }
        __syncthreads();
    }
}

// ---------------- launch ----------------

extern "C" void kernel_launch(void* const* d_in, const int* in_sizes, int n_in,
                              void* d_out, int out_size, void* d_ws, size_t ws_size,
                              hipStream_t stream) {
    const float* rgb = (const float*)d_in[0];
    const float* ir  = (const float*)d_in[1];
    const int*   ei  = (const int*)d_in[2];
    const float* pos = (const float*)d_in[3];
    const float* Wg  = (const float*)d_in[4];
    const float* bg  = (const float*)d_in[5];
    const float* lw  = (const float*)d_in[6];
    const float* lb  = (const float*)d_in[7];
    float* out = (float*)d_out;

    char* ws = (char*)d_ws;
    ushort* x0h  = (ushort*)(ws);
    ushort* x0l  = (ushort*)(ws + 8388608);
    ushort* x1h  = (ushort*)(ws + 16777216);
    ushort* x1l  = (ushort*)(ws + 25165824);
    ushort* Wfh  = (ushort*)(ws + 33554432);
    ushort* Wfl  = (ushort*)(ws + 37748736);
    ushort* Afh  = (ushort*)(ws + 42009088);
    ushort* Afl  = (ushort*)(ws + 42041856);

    prep_k<<<1, 256, 0, stream>>>(ei, Afh, Afl);

    front_k<<<2560, 256, 0, stream>>>(rgb, ir, pos, Wg, x0h, x0l, Wfh, Wfl);

    for (int l = 0; l < NLAYERS; ++l) {
        const ushort* inh = (l & 1) ? x1h : x0h;
        const ushort* inl = (l & 1) ? x1l : x0l;
        ushort* outh = (l & 1) ? x0h : x1h;
        ushort* outl = (l & 1) ? x0l : x1l;
        gemm_fused_k<<<512, 256, 0, stream>>>(
            inh, inl, Wfh + (size_t)l * C_ * C_, Wfl + (size_t)l * C_ * C_,
            Afh, Afl, bg + (size_t)l * C_, outh, outl);
    }

    ln_out_k<<<2 * B_, 256, 0, stream>>>(x0h, x0l, lw, lb, out);
}